// Round 17
// baseline (166.675 us; speedup 1.0000x reference)
//
#include <hip/hip_runtime.h>
#include <math.h>

#define N_NODES 50000
#define N_EDGES 800000
#define BSH 7                                    // 128 nodes per bucket
#define BNODES 128
#define NBKT ((N_NODES + BNODES - 1) / BNODES)   // 391
#define CAP 2560                                 // padded edges per bucket (mean 2048 + 11 sigma)
#define EPW 4096                                 // edges per block in phaseA
#define NWG_A ((N_EDGES + EPW - 1) / EPW)        // 196

typedef _Float16 half4_t __attribute__((ext_vector_type(4)));
typedef _Float16 half8_t __attribute__((ext_vector_type(8)));
typedef float floatx4 __attribute__((ext_vector_type(4)));

// ---------------------------------------------------------------------------
// LESSONS (keep):
//  r10/r11: column-partitioned gathers REGRESS vs full-row (same h-lines
//    re-fetched; h not XCD-L2 resident; blockIdx->XCD residency unrealizable).
//  r12: gather is L3-path bound (~114MB FETCH @ ~3.3TB/s); deeper unroll=noise.
//  r13: EPW=16384 bucketA / 512-thr matmul regressed. Keep EPW=4096.
//  r14: cooperative grid.sync() costs ~65us each on MI355X -> never for short
//    phases. Fuse by restructuring deps (padded buckets, local scans) = r15 win.
//  r16: mm A-path direct-from-global (A-fragment of 16x16x32 = native 16B/lane
//    line-granular loads) — no As LDS needed for matmul.
//  r17: gmm fusion preserves the gather phase shape EXACTLY (TPN=16, same
//    unroll/occupancy); MFMA is a cheap tail with B direct from L2-hot Wt.
//
// Workspace layout:
//   flag    : int[64]
//   bcur    : int[448]
//   dinv    : float[50048]
//   rowptr  : int[50048]     beg = b*CAP + local_excl
//   deg16   : ushort[50048]
//   ep2     : uint[391*2560] bucket-grouped packed edges (src | dst<<16)
//   csr_src : ushort[391*2560]
//   Wt1/2/3 : fp16 W^T
//   h, agg  : fp16[50000*128] (ping-pong feature buffers)
// ---------------------------------------------------------------------------

__device__ __forceinline__ void load_edge(const int* ei, int is64, int e, int& s, int& d) {
    if (is64) {
        const long long* q = (const long long*)ei;
        s = (int)q[e];
        d = (int)q[N_EDGES + e];
    } else {
        s = ei[e];
        d = ei[N_EDGES + e];
    }
}

// init: detect i64, zero bucket counters, weight cast/transpose. 161 blocks.
__global__ void init_k(const int* ei, int* flag, int* bcur,
                       const float* __restrict__ W1, const float* __restrict__ W2,
                       const float* __restrict__ W3,
                       _Float16* __restrict__ Wt1, _Float16* __restrict__ Wt2,
                       _Float16* __restrict__ Wt3) {
    int i = blockIdx.x * 256 + threadIdx.x;
    if (i < 448) bcur[i] = 0;
    if (i == 0) {
        int orr = 0;
        for (int j = 0; j < 16; ++j) orr |= ei[2 * j + 1];
        *flag = (orr == 0) ? 1 : 0;
    }
    if (i < 16384) {
        int k = i >> 7, c = i & 127;           // W1[128][128]
        Wt1[c * 128 + k] = (_Float16)W1[i];
    } else if (i < 32768) {
        int j = i - 16384;
        int k = j >> 7, c = j & 127;           // W2[128][128]
        Wt2[c * 128 + k] = (_Float16)W2[j];
    } else if (i < 40960) {
        int j = i - 32768;
        int k = j >> 6, c = j & 63;            // W3[128][64]
        Wt3[c * 128 + k] = (_Float16)W3[j];
    }
}

// phaseA: pack edges, group by dst-bucket into padded regions ep2[b*CAP..].
__global__ __launch_bounds__(256) void phaseA_k(const int* __restrict__ ei,
                                                const int* flag, int* bcur,
                                                unsigned int* __restrict__ ep2) {
    __shared__ int hist[NBKT];
    __shared__ int gofs[NBKT];
    __shared__ int lcur[NBKT];
    int tid = threadIdx.x;
    for (int i = tid; i < NBKT; i += 256) { hist[i] = 0; lcur[i] = 0; }
    __syncthreads();
    int base = blockIdx.x * EPW;
    int is64 = *flag;
    unsigned int pv[EPW / 256];
#pragma unroll
    for (int j = 0; j < EPW / 256; ++j) {
        int e = base + j * 256 + tid;
        unsigned int p = 0xFFFFFFFFu;
        if (e < N_EDGES) {
            int s, d;
            load_edge(ei, is64, e, s, d);
            p = (unsigned int)s | ((unsigned int)d << 16);
            atomicAdd(&hist[d >> BSH], 1);
        }
        pv[j] = p;
    }
    __syncthreads();
    for (int i = tid; i < NBKT; i += 256)
        gofs[i] = hist[i] ? atomicAdd(&bcur[i], hist[i]) : 0;
    __syncthreads();
#pragma unroll
    for (int j = 0; j < EPW / 256; ++j) {
        unsigned int p = pv[j];
        if (p == 0xFFFFFFFFu) continue;
        int b = (int)(p >> 16) >> BSH;
        int pos = gofs[b] + atomicAdd(&lcur[b], 1);
        ep2[(size_t)b * CAP + pos] = p;
    }
}

// bucketB2: one block per bucket. LDS per-node histogram, LDS scan ->
// rowptr/deg16/dinv, LDS-cursor fill of csr_src.
__global__ __launch_bounds__(256) void bucketB2_k(const unsigned int* __restrict__ ep2,
                                                  const int* __restrict__ bcur,
                                                  unsigned short* __restrict__ csr_src,
                                                  int* __restrict__ rowptr,
                                                  unsigned short* __restrict__ deg16,
                                                  float* __restrict__ dinv) {
    __shared__ int ncnt[BNODES];
    __shared__ int excl[BNODES];
    __shared__ int cur[BNODES];
    int b = blockIdx.x;
    int lo = b << BSH;
    int tid = threadIdx.x;
    int cnt_b = min(bcur[b], CAP);
    const unsigned int* reg = ep2 + (size_t)b * CAP;
    if (tid < BNODES) ncnt[tid] = 0;
    __syncthreads();
    for (int j = tid; j < cnt_b; j += 256)
        atomicAdd(&ncnt[(int)(reg[j] >> 16) - lo], 1);
    __syncthreads();
    if (tid < BNODES) excl[tid] = ncnt[tid];
    __syncthreads();
#pragma unroll
    for (int off = 1; off < BNODES; off <<= 1) {
        int t = (tid < BNODES && tid >= off) ? excl[tid - off] : 0;
        __syncthreads();
        if (tid < BNODES) excl[tid] += t;
        __syncthreads();
    }
    if (tid < BNODES) {
        int v = ncnt[tid];
        int ex = excl[tid] - v;   // exclusive
        cur[tid] = ex;
        int n = lo + tid;
        if (n < N_NODES) {
            rowptr[n] = b * CAP + ex;
            deg16[n] = (unsigned short)v;
            dinv[n] = rsqrtf(1.0f + (float)v);
        }
    }
    __syncthreads();
    for (int j = tid; j < cnt_b; j += 256) {
        unsigned int p = reg[j];
        int dl = (int)(p >> 16) - lo;
        int slot = atomicAdd(&cur[dl], 1);
        csr_src[(size_t)b * CAP + slot] = (unsigned short)(p & 0xFFFFu);
    }
}

// mm1: hs[N][128] = (x[N][128] @ W1) * dinv[row], fp16 out. A direct-from-
// global (r16-proven), Wt LDS-staged. 256 thr, 64 rows/block.
__global__ __launch_bounds__(256) void mm1_k(const float* __restrict__ A,
                                             const _Float16* __restrict__ Wt,
                                             const float* __restrict__ dinv,
                                             _Float16* __restrict__ C) {
    constexpr int AST = 128 + 8;
    __shared__ _Float16 Ws[128 * AST];
    const int tid = threadIdx.x;
    const int rowBase = blockIdx.x * 64;

    for (int i = tid; i < 128 * 16; i += 256) {
        int r = i >> 4;
        int k8 = (i & 15) * 8;
        *(half8_t*)&Ws[r * AST + k8] = *(const half8_t*)(Wt + r * 128 + k8);
    }

    const int wid = tid >> 6;
    const int lane = tid & 63;
    const int l15 = lane & 15;
    const int lk = (lane >> 4) * 8;
    const int wrow = wid * 16;
    const int grow = rowBase + wrow + l15;
    const bool rowok = grow < N_NODES;

    half8_t afv[4];
#pragma unroll
    for (int kc = 0; kc < 4; ++kc) {
        half8_t af = {};
        if (rowok) {
            const float* ap = A + (size_t)grow * 128 + kc * 32 + lk;
            float4 a0 = *(const float4*)ap;
            float4 a1 = *(const float4*)(ap + 4);
            float t[8] = {a0.x, a0.y, a0.z, a0.w, a1.x, a1.y, a1.z, a1.w};
#pragma unroll
            for (int j = 0; j < 8; ++j) af[j] = (_Float16)t[j];
        }
        afv[kc] = af;
    }
    __syncthreads();

    floatx4 acc[8];
#pragma unroll
    for (int t = 0; t < 8; ++t) acc[t] = (floatx4){0.f, 0.f, 0.f, 0.f};
#pragma unroll
    for (int kc = 0; kc < 4; ++kc) {
#pragma unroll
        for (int ct = 0; ct < 8; ++ct) {
            half8_t bf = *(const half8_t*)&Ws[(ct * 16 + l15) * AST + kc * 32 + lk];
            acc[ct] = __builtin_amdgcn_mfma_f32_16x16x32_f16(afv[kc], bf, acc[ct], 0, 0, 0);
        }
    }
    int rloc = wrow + (lane >> 4) * 4;
#pragma unroll
    for (int q = 0; q < 4; ++q) {
        int gr = rowBase + rloc + q;
        if (gr < N_NODES) {
            float dn = dinv[gr];
#pragma unroll
            for (int ct = 0; ct < 8; ++ct) {
                C[(size_t)gr * 128 + ct * 16 + l15] = (_Float16)(acc[ct][q] * dn);
            }
        }
    }
}

// gmm: FUSED gather(layer L) + matmul(layer L+1).
//   row[n] = relu( dinv[n]*(sum_e hin[src] + hin[n]) + bias )   -> As (LDS)
//   hout[n] = (row @ W_{L+1}) * dinv[n]                          (fp16)
// 1024 thr = 64 nodes x TPN=16 (gather shape IDENTICAL to proven gather_k).
// MFMA tail: 16 waves x PPW (row-tile,ct) pairs; B read direct from L2-hot Wt.
template <int DOUT>
__global__ __launch_bounds__(1024) void gmm_k(const _Float16* __restrict__ hin,
                                              const int* __restrict__ rowptr,
                                              const unsigned short* __restrict__ deg16,
                                              const unsigned short* __restrict__ csr_src,
                                              const float* __restrict__ dinv,
                                              const float* __restrict__ bias,
                                              const _Float16* __restrict__ Wt,
                                              _Float16* __restrict__ hout) {
    constexpr int AST = 128 + 8;
    __shared__ _Float16 As[64 * AST];
    const int tid = threadIdx.x;
    const int rowBase = blockIdx.x * 64;
    const int ng = tid >> 4;          // node index in block (0..63)
    const int li = tid & 15;          // feature lane (8 feats each)
    const int n = rowBase + ng;

    // ---- gather phase (structure identical to gather_k<128>) ----
    if (n < N_NODES) {
        const _Float16* hp = hin + li * 8;
        int beg = rowptr[n];
        int end = beg + deg16[n];
        float acc[8], acc2[8];
#pragma unroll
        for (int j = 0; j < 8; ++j) { acc[j] = 0.f; acc2[j] = 0.f; }
        int e = beg;
        for (; e + 8 <= end; e += 8) {
            int s0 = csr_src[e];
            int s1 = csr_src[e + 1];
            int s2 = csr_src[e + 2];
            int s3 = csr_src[e + 3];
            int s4 = csr_src[e + 4];
            int s5 = csr_src[e + 5];
            int s6 = csr_src[e + 6];
            int s7 = csr_src[e + 7];
            half8_t v0 = *(const half8_t*)(hp + (size_t)s0 * 128);
            half8_t v1 = *(const half8_t*)(hp + (size_t)s1 * 128);
            half8_t v2 = *(const half8_t*)(hp + (size_t)s2 * 128);
            half8_t v3 = *(const half8_t*)(hp + (size_t)s3 * 128);
            half8_t v4 = *(const half8_t*)(hp + (size_t)s4 * 128);
            half8_t v5 = *(const half8_t*)(hp + (size_t)s5 * 128);
            half8_t v6 = *(const half8_t*)(hp + (size_t)s6 * 128);
            half8_t v7 = *(const half8_t*)(hp + (size_t)s7 * 128);
#pragma unroll
            for (int j = 0; j < 8; ++j) {
                acc[j] += (float)v0[j];
                acc2[j] += (float)v1[j];
                acc[j] += (float)v2[j];
                acc2[j] += (float)v3[j];
                acc[j] += (float)v4[j];
                acc2[j] += (float)v5[j];
                acc[j] += (float)v6[j];
                acc2[j] += (float)v7[j];
            }
        }
        for (; e + 2 <= end; e += 2) {
            int s0 = csr_src[e];
            int s1 = csr_src[e + 1];
            half8_t v0 = *(const half8_t*)(hp + (size_t)s0 * 128);
            half8_t v1 = *(const half8_t*)(hp + (size_t)s1 * 128);
#pragma unroll
            for (int j = 0; j < 8; ++j) {
                acc[j] += (float)v0[j];
                acc2[j] += (float)v1[j];
            }
        }
        if (e < end) {
            int s0 = csr_src[e];
            half8_t v0 = *(const half8_t*)(hp + (size_t)s0 * 128);
#pragma unroll
            for (int j = 0; j < 8; ++j) acc[j] += (float)v0[j];
        }
        float dn = dinv[n];
        half8_t hv = *(const half8_t*)(hp + (size_t)n * 128);
        float4 bv0 = *(const float4*)(bias + li * 8);
        float4 bv1 = *(const float4*)(bias + li * 8 + 4);
        float r[8];
        r[0] = (acc[0] + acc2[0] + (float)hv[0]) * dn + bv0.x;
        r[1] = (acc[1] + acc2[1] + (float)hv[1]) * dn + bv0.y;
        r[2] = (acc[2] + acc2[2] + (float)hv[2]) * dn + bv0.z;
        r[3] = (acc[3] + acc2[3] + (float)hv[3]) * dn + bv0.w;
        r[4] = (acc[4] + acc2[4] + (float)hv[4]) * dn + bv1.x;
        r[5] = (acc[5] + acc2[5] + (float)hv[5]) * dn + bv1.y;
        r[6] = (acc[6] + acc2[6] + (float)hv[6]) * dn + bv1.z;
        r[7] = (acc[7] + acc2[7] + (float)hv[7]) * dn + bv1.w;
        half8_t oV;
#pragma unroll
        for (int j = 0; j < 8; ++j) oV[j] = (_Float16)fmaxf(r[j], 0.f);   // relu
        *(half8_t*)&As[ng * AST + li * 8] = oV;
    } else {
        half8_t z = {};
        *(half8_t*)&As[ng * AST + li * 8] = z;
    }
    __syncthreads();

    // ---- MFMA tail: hout = As @ Wt^T, x dinv ----
    const int wid = tid >> 6;          // 0..15
    const int lane = tid & 63;
    const int l15 = lane & 15;
    const int lk = (lane >> 4) * 8;
    constexpr int NCT = DOUT / 16;     // 8 or 4
    constexpr int NP = 4 * NCT;        // (row-tile, ct) pairs: 32 or 16
    constexpr int PPW = (NP + 15) / 16;
#pragma unroll
    for (int j = 0; j < PPW; ++j) {
        int p = wid * PPW + j;
        if (p < NP) {
            int rt = p / NCT;
            int ct = p % NCT;
            floatx4 acc = (floatx4){0.f, 0.f, 0.f, 0.f};
#pragma unroll
            for (int kc = 0; kc < 4; ++kc) {
                half8_t af = *(const half8_t*)&As[(rt * 16 + l15) * AST + kc * 32 + lk];
                half8_t bf = *(const half8_t*)(Wt + (ct * 16 + l15) * 128 + kc * 32 + lk);
                acc = __builtin_amdgcn_mfma_f32_16x16x32_f16(af, bf, acc, 0, 0, 0);
            }
            int rloc = rt * 16 + (lane >> 4) * 4;
#pragma unroll
            for (int q = 0; q < 4; ++q) {
                int gr = rowBase + rloc + q;
                if (gr < N_NODES) {
                    hout[(size_t)gr * DOUT + ct * 16 + l15] =
                        (_Float16)(acc[q] * dinv[gr]);
                }
            }
        }
    }
}

// Final pull aggregation (layer 3): out[n] = dinv[n]*(sum hs[src]+hs[n]) + b, f32.
__global__ __launch_bounds__(256) void gather3_k(const _Float16* __restrict__ h,
                                                 const int* __restrict__ rowptr,
                                                 const unsigned short* __restrict__ deg16,
                                                 const unsigned short* __restrict__ csr_src,
                                                 const float* __restrict__ dinv,
                                                 const float* __restrict__ b,
                                                 float* __restrict__ out) {
    constexpr int DOUT = 64;
    constexpr int TPN = DOUT / 8;   // 8
    constexpr int NPB = 256 / TPN;  // 32
    int n = blockIdx.x * NPB + threadIdx.x / TPN;
    int li = threadIdx.x % TPN;
    if (n >= N_NODES) return;
    const _Float16* hp = h + li * 8;
    int beg = rowptr[n];
    int end = beg + deg16[n];
    float acc[8], acc2[8];
#pragma unroll
    for (int j = 0; j < 8; ++j) { acc[j] = 0.f; acc2[j] = 0.f; }
    int e = beg;
    for (; e + 8 <= end; e += 8) {
        int s0 = csr_src[e];
        int s1 = csr_src[e + 1];
        int s2 = csr_src[e + 2];
        int s3 = csr_src[e + 3];
        int s4 = csr_src[e + 4];
        int s5 = csr_src[e + 5];
        int s6 = csr_src[e + 6];
        int s7 = csr_src[e + 7];
        half8_t v0 = *(const half8_t*)(hp + (size_t)s0 * DOUT);
        half8_t v1 = *(const half8_t*)(hp + (size_t)s1 * DOUT);
        half8_t v2 = *(const half8_t*)(hp + (size_t)s2 * DOUT);
        half8_t v3 = *(const half8_t*)(hp + (size_t)s3 * DOUT);
        half8_t v4 = *(const half8_t*)(hp + (size_t)s4 * DOUT);
        half8_t v5 = *(const half8_t*)(hp + (size_t)s5 * DOUT);
        half8_t v6 = *(const half8_t*)(hp + (size_t)s6 * DOUT);
        half8_t v7 = *(const half8_t*)(hp + (size_t)s7 * DOUT);
#pragma unroll
        for (int j = 0; j < 8; ++j) {
            acc[j] += (float)v0[j];
            acc2[j] += (float)v1[j];
            acc[j] += (float)v2[j];
            acc2[j] += (float)v3[j];
            acc[j] += (float)v4[j];
            acc2[j] += (float)v5[j];
            acc[j] += (float)v6[j];
            acc2[j] += (float)v7[j];
        }
    }
    for (; e + 2 <= end; e += 2) {
        int s0 = csr_src[e];
        int s1 = csr_src[e + 1];
        half8_t v0 = *(const half8_t*)(hp + (size_t)s0 * DOUT);
        half8_t v1 = *(const half8_t*)(hp + (size_t)s1 * DOUT);
#pragma unroll
        for (int j = 0; j < 8; ++j) {
            acc[j] += (float)v0[j];
            acc2[j] += (float)v1[j];
        }
    }
    if (e < end) {
        int s0 = csr_src[e];
        half8_t v0 = *(const half8_t*)(hp + (size_t)s0 * DOUT);
#pragma unroll
        for (int j = 0; j < 8; ++j) acc[j] += (float)v0[j];
    }
    float dn = dinv[n];
    half8_t hv = *(const half8_t*)(hp + (size_t)n * DOUT);
    float4 bv0 = *(const float4*)(b + li * 8);
    float4 bv1 = *(const float4*)(b + li * 8 + 4);
    float* op = out + (size_t)n * DOUT + li * 8;
    *(float4*)op = make_float4(
        (acc[0] + acc2[0] + (float)hv[0]) * dn + bv0.x,
        (acc[1] + acc2[1] + (float)hv[1]) * dn + bv0.y,
        (acc[2] + acc2[2] + (float)hv[2]) * dn + bv0.z,
        (acc[3] + acc2[3] + (float)hv[3]) * dn + bv0.w);
    *(float4*)(op + 4) = make_float4(
        (acc[4] + acc2[4] + (float)hv[4]) * dn + bv1.x,
        (acc[5] + acc2[5] + (float)hv[5]) * dn + bv1.y,
        (acc[6] + acc2[6] + (float)hv[6]) * dn + bv1.z,
        (acc[7] + acc2[7] + (float)hv[7]) * dn + bv1.w);
}

extern "C" void kernel_launch(void* const* d_in, const int* in_sizes, int n_in,
                              void* d_out, int out_size, void* d_ws, size_t ws_size,
                              hipStream_t stream) {
    const float* x  = (const float*)d_in[0];
    const int*   ei = (const int*)d_in[1];
    const float* W1 = (const float*)d_in[2];
    const float* b1 = (const float*)d_in[3];
    const float* W2 = (const float*)d_in[4];
    const float* b2 = (const float*)d_in[5];
    const float* W3 = (const float*)d_in[6];
    const float* b3 = (const float*)d_in[7];
    float* out = (float*)d_out;

    char* wsb = (char*)d_ws;
    size_t o = 0;
    int*            flag     = (int*)(wsb + o); o += 64 * 4;
    int*            bcur     = (int*)(wsb + o); o += 448 * 4;
    float*          dinv     = (float*)(wsb + o); o += 50048 * 4;
    int*            rowptr   = (int*)(wsb + o); o += 50048 * 4;
    unsigned short* deg16    = (unsigned short*)(wsb + o); o += 50048 * 2;
    unsigned int*   ep2      = (unsigned int*)(wsb + o); o += (size_t)NBKT * CAP * 4;
    unsigned short* csr_src  = (unsigned short*)(wsb + o); o += (size_t)NBKT * CAP * 2;
    _Float16*       Wt1      = (_Float16*)(wsb + o); o += 128 * 128 * 2;
    _Float16*       Wt2      = (_Float16*)(wsb + o); o += 128 * 128 * 2;
    _Float16*       Wt3      = (_Float16*)(wsb + o); o += 64 * 128 * 2;
    _Float16*       h        = (_Float16*)(wsb + o); o += (size_t)N_NODES * 128 * 2;
    _Float16*       agg      = (_Float16*)(wsb + o);

    const int MMB = (N_NODES + 63) / 64;   // 782

    // ---- graph preprocessing: 3 launches, no global scan ----
    init_k<<<161, 256, 0, stream>>>(ei, flag, bcur, W1, W2, W3, Wt1, Wt2, Wt3);
    phaseA_k<<<NWG_A, 256, 0, stream>>>(ei, flag, bcur, ep2);
    bucketB2_k<<<NBKT, 256, 0, stream>>>(ep2, bcur, csr_src, rowptr, deg16, dinv);

    // ---- layer 1 transform ----
    mm1_k<<<MMB, 256, 0, stream>>>(x, Wt1, dinv, h);

    // ---- fused gather1 + transform2 ----
    gmm_k<128><<<MMB, 1024, 0, stream>>>(h, rowptr, deg16, csr_src, dinv, b1, Wt2, agg);

    // ---- fused gather2 + transform3 ----
    gmm_k<64><<<MMB, 1024, 0, stream>>>(agg, rowptr, deg16, csr_src, dinv, b2, Wt3, h);

    // ---- final gather (to d_out, f32) ----
    gather3_k<<<(N_NODES + 31) / 32, 256, 0, stream>>>(h, rowptr, deg16, csr_src, dinv, b3, out);
}

// Round 18
// 147.954 us; speedup vs baseline: 1.1265x; 1.1265x over previous
//
#include <hip/hip_runtime.h>
#include <math.h>

#define N_NODES 50000
#define N_EDGES 800000
#define BSH 7                                    // 128 nodes per bucket
#define BNODES 128
#define NBKT ((N_NODES + BNODES - 1) / BNODES)   // 391
#define CAP 2560                                 // padded edges per bucket (mean 2048 + 11 sigma)
#define EPW 4096                                 // edges per block in phaseA
#define NWG_A ((N_EDGES + EPW - 1) / EPW)        // 196

typedef _Float16 half4_t __attribute__((ext_vector_type(4)));
typedef _Float16 half8_t __attribute__((ext_vector_type(8)));
typedef float floatx4 __attribute__((ext_vector_type(4)));

// ---------------------------------------------------------------------------
// LESSONS (keep):
//  r10/r11: column-partitioned gathers REGRESS vs full-row (same h-lines
//    re-fetched; h not XCD-L2 resident; blockIdx->XCD residency unrealizable).
//  r12: gather is L3-path bound (~114MB FETCH @ ~3.3TB/s); deeper unroll=noise.
//  r13: EPW=16384 bucketA / 512-thr matmul regressed. Keep EPW=4096.
//  r14: cooperative grid.sync() costs ~65us each on MI355X -> never for short
//    phases. Fuse by restructuring deps (padded buckets, local scans) = r15 win.
//  r16: mm A-path direct-from-global (A-fragment of 16x16x32 = native 16B/lane
//    line-granular loads) — no As LDS needed for matmul. PROVEN 148us state.
//  r17: gmm (gather+matmul barrier-fused, 1024thr) REGRESSED 148->167:
//    barrier couples all 16 waves to slowest node's gather (degree-variance
//    tail) and coarse 1024-thr blocks lose wave-level TLP (occ 70%->32%).
//    Don't couple latency-bound irregular phases to barriers+compute tails.
//
// Workspace layout:
//   flag    : int[64]
//   bcur    : int[448]       per-bucket reservation counters (zeroed per call)
//   dinv    : float[50048]
//   rowptr  : int[50048]     beg = b*CAP + local_excl
//   deg16   : ushort[50048]
//   ep2     : uint[391*2560] bucket-grouped packed edges (src | dst<<16)
//   csr_src : ushort[391*2560]
//   Wt1/2/3 : fp16 W^T
//   h       : fp16[50000*128]
//   agg     : fp16[50000*128]
// ---------------------------------------------------------------------------

__device__ __forceinline__ void load_edge(const int* ei, int is64, int e, int& s, int& d) {
    if (is64) {
        const long long* q = (const long long*)ei;
        s = (int)q[e];
        d = (int)q[N_EDGES + e];
    } else {
        s = ei[e];
        d = ei[N_EDGES + e];
    }
}

// init: detect i64, zero bucket counters, weight cast/transpose. 161 blocks.
__global__ void init_k(const int* ei, int* flag, int* bcur,
                       const float* __restrict__ W1, const float* __restrict__ W2,
                       const float* __restrict__ W3,
                       _Float16* __restrict__ Wt1, _Float16* __restrict__ Wt2,
                       _Float16* __restrict__ Wt3) {
    int i = blockIdx.x * 256 + threadIdx.x;
    if (i < 448) bcur[i] = 0;
    if (i == 0) {
        int orr = 0;
        for (int j = 0; j < 16; ++j) orr |= ei[2 * j + 1];
        *flag = (orr == 0) ? 1 : 0;
    }
    if (i < 16384) {
        int k = i >> 7, c = i & 127;           // W1[128][128]
        Wt1[c * 128 + k] = (_Float16)W1[i];
    } else if (i < 32768) {
        int j = i - 16384;
        int k = j >> 7, c = j & 127;           // W2[128][128]
        Wt2[c * 128 + k] = (_Float16)W2[j];
    } else if (i < 40960) {
        int j = i - 32768;
        int k = j >> 6, c = j & 63;            // W3[128][64]
        Wt3[c * 128 + k] = (_Float16)W3[j];
    }
}

// phaseA: read edge list directly, pack, group by dst-bucket into padded
// regions ep2[b*CAP ...]. LDS histogram -> one global reservation per
// (block,bucket) -> scatter.
__global__ __launch_bounds__(256) void phaseA_k(const int* __restrict__ ei,
                                                const int* flag, int* bcur,
                                                unsigned int* __restrict__ ep2) {
    __shared__ int hist[NBKT];
    __shared__ int gofs[NBKT];
    __shared__ int lcur[NBKT];
    int tid = threadIdx.x;
    for (int i = tid; i < NBKT; i += 256) { hist[i] = 0; lcur[i] = 0; }
    __syncthreads();
    int base = blockIdx.x * EPW;
    int is64 = *flag;
    unsigned int pv[EPW / 256];
#pragma unroll
    for (int j = 0; j < EPW / 256; ++j) {
        int e = base + j * 256 + tid;
        unsigned int p = 0xFFFFFFFFu;
        if (e < N_EDGES) {
            int s, d;
            load_edge(ei, is64, e, s, d);
            p = (unsigned int)s | ((unsigned int)d << 16);
            atomicAdd(&hist[d >> BSH], 1);
        }
        pv[j] = p;
    }
    __syncthreads();
    for (int i = tid; i < NBKT; i += 256)
        gofs[i] = hist[i] ? atomicAdd(&bcur[i], hist[i]) : 0;
    __syncthreads();
#pragma unroll
    for (int j = 0; j < EPW / 256; ++j) {
        unsigned int p = pv[j];
        if (p == 0xFFFFFFFFu) continue;
        int b = (int)(p >> 16) >> BSH;
        int pos = gofs[b] + atomicAdd(&lcur[b], 1);
        ep2[(size_t)b * CAP + pos] = p;
    }
}

// bucketB2: one block per bucket. LDS per-node histogram over its region,
// LDS scan -> rowptr/deg16/dinv, then LDS-cursor fill of csr_src.
__global__ __launch_bounds__(256) void bucketB2_k(const unsigned int* __restrict__ ep2,
                                                  const int* __restrict__ bcur,
                                                  unsigned short* __restrict__ csr_src,
                                                  int* __restrict__ rowptr,
                                                  unsigned short* __restrict__ deg16,
                                                  float* __restrict__ dinv) {
    __shared__ int ncnt[BNODES];
    __shared__ int excl[BNODES];
    __shared__ int cur[BNODES];
    int b = blockIdx.x;
    int lo = b << BSH;
    int tid = threadIdx.x;
    int cnt_b = min(bcur[b], CAP);
    const unsigned int* reg = ep2 + (size_t)b * CAP;
    if (tid < BNODES) ncnt[tid] = 0;
    __syncthreads();
    for (int j = tid; j < cnt_b; j += 256)
        atomicAdd(&ncnt[(int)(reg[j] >> 16) - lo], 1);
    __syncthreads();
    if (tid < BNODES) excl[tid] = ncnt[tid];
    __syncthreads();
#pragma unroll
    for (int off = 1; off < BNODES; off <<= 1) {
        int t = (tid < BNODES && tid >= off) ? excl[tid - off] : 0;
        __syncthreads();
        if (tid < BNODES) excl[tid] += t;
        __syncthreads();
    }
    if (tid < BNODES) {
        int v = ncnt[tid];
        int ex = excl[tid] - v;   // exclusive
        cur[tid] = ex;
        int n = lo + tid;
        if (n < N_NODES) {
            rowptr[n] = b * CAP + ex;
            deg16[n] = (unsigned short)v;
            dinv[n] = rsqrtf(1.0f + (float)v);
        }
    }
    __syncthreads();
    for (int j = tid; j < cnt_b; j += 256) {
        unsigned int p = reg[j];
        int dl = (int)(p >> 16) - lo;
        int slot = atomicAdd(&cur[dl], 1);
        csr_src[(size_t)b * CAP + slot] = (unsigned short)(p & 0xFFFFu);
    }
}

// hs[N][DOUT] = (relu(A)[N][128] @ W[128][DOUT]) * dinv[row], fp16 out.
// MFMA 16x16x32 f16, f32 accumulate. 256 thr = 4 waves, 64 rows/block.
// A fragments loaded DIRECT from global (16B/lane, line-granular: a wave at
// fixed kc reads 16 rows x 64B = 16 full lines) — no As LDS, no staging loop.
// Only Wt is LDS-staged (reused by all 64 rows).
template <int DOUT, bool RELU, typename TIN>
__global__ __launch_bounds__(256) void mm_mfma_k(const TIN* __restrict__ A,
                                                 const _Float16* __restrict__ Wt,
                                                 const float* __restrict__ dinv,
                                                 _Float16* __restrict__ C) {
    constexpr int AST = 128 + 8;   // padded fp16 row stride (bank-spread)
    __shared__ _Float16 Ws[DOUT * AST];
    const int tid = threadIdx.x;
    const int rowBase = blockIdx.x * 64;

    for (int i = tid; i < DOUT * 16; i += 256) {
        int r = i >> 4;
        int k8 = (i & 15) * 8;
        *(half8_t*)&Ws[r * AST + k8] = *(const half8_t*)(Wt + r * 128 + k8);
    }

    const int wid = tid >> 6;
    const int lane = tid & 63;
    const int l15 = lane & 15;
    const int lk = (lane >> 4) * 8;
    const int wrow = wid * 16;
    const int grow = rowBase + wrow + l15;     // A-row this lane reads
    const bool rowok = grow < N_NODES;

    // load all 4 k-chunk A-fragments up front (overlaps with Ws staging)
    half8_t afv[4];
#pragma unroll
    for (int kc = 0; kc < 4; ++kc) {
        half8_t af = {};
        if (rowok) {
            if constexpr (sizeof(TIN) == 4) {
                const float* ap = (const float*)A + (size_t)grow * 128 + kc * 32 + lk;
                float4 a0 = *(const float4*)ap;
                float4 a1 = *(const float4*)(ap + 4);
                float t[8] = {a0.x, a0.y, a0.z, a0.w, a1.x, a1.y, a1.z, a1.w};
#pragma unroll
                for (int j = 0; j < 8; ++j)
                    af[j] = (_Float16)(RELU ? fmaxf(t[j], 0.f) : t[j]);
            } else {
                af = *(const half8_t*)((const _Float16*)A + (size_t)grow * 128 + kc * 32 + lk);
                if (RELU) {
#pragma unroll
                    for (int j = 0; j < 8; ++j)
                        af[j] = (af[j] > (_Float16)0) ? af[j] : (_Float16)0;
                }
            }
        }
        afv[kc] = af;
    }
    __syncthreads();   // Ws ready

    floatx4 acc[DOUT / 16];
#pragma unroll
    for (int t = 0; t < DOUT / 16; ++t) acc[t] = (floatx4){0.f, 0.f, 0.f, 0.f};

#pragma unroll
    for (int kc = 0; kc < 4; ++kc) {
#pragma unroll
        for (int ct = 0; ct < DOUT / 16; ++ct) {
            half8_t bf = *(const half8_t*)&Ws[(ct * 16 + l15) * AST + kc * 32 + lk];
            acc[ct] = __builtin_amdgcn_mfma_f32_16x16x32_f16(afv[kc], bf, acc[ct], 0, 0, 0);
        }
    }

    // D: row = (lane>>4)*4 + q, col = ct*16 + (lane&15)
    int rloc = wrow + (lane >> 4) * 4;
#pragma unroll
    for (int q = 0; q < 4; ++q) {
        int gr = rowBase + rloc + q;
        if (gr < N_NODES) {
            float dn = dinv[gr];
#pragma unroll
            for (int ct = 0; ct < DOUT / 16; ++ct) {
                C[(size_t)gr * DOUT + ct * 16 + l15] = (_Float16)(acc[ct][q] * dn);
            }
        }
    }
}

// Pull aggregation (FULL-ROW, proven form):
//   out[n] = dinv[n] * (sum_e hs[src[e]] + hs[n]) + b
template <int DOUT, bool F16OUT>
__global__ __launch_bounds__(256) void gather_k(const _Float16* __restrict__ h,
                                                const int* __restrict__ rowptr,
                                                const unsigned short* __restrict__ deg16,
                                                const unsigned short* __restrict__ csr_src,
                                                const float* __restrict__ dinv,
                                                const float* __restrict__ b,
                                                void* __restrict__ out) {
    constexpr int TPN = DOUT / 8;
    constexpr int NPB = 256 / TPN;
    int n = blockIdx.x * NPB + threadIdx.x / TPN;
    int li = threadIdx.x % TPN;
    if (n >= N_NODES) return;
    const _Float16* hp = h + li * 8;
    int beg = rowptr[n];
    int end = beg + deg16[n];
    float acc[8], acc2[8];
#pragma unroll
    for (int j = 0; j < 8; ++j) { acc[j] = 0.f; acc2[j] = 0.f; }
    int e = beg;
    for (; e + 8 <= end; e += 8) {
        int s0 = csr_src[e];
        int s1 = csr_src[e + 1];
        int s2 = csr_src[e + 2];
        int s3 = csr_src[e + 3];
        int s4 = csr_src[e + 4];
        int s5 = csr_src[e + 5];
        int s6 = csr_src[e + 6];
        int s7 = csr_src[e + 7];
        half8_t v0 = *(const half8_t*)(hp + (size_t)s0 * DOUT);
        half8_t v1 = *(const half8_t*)(hp + (size_t)s1 * DOUT);
        half8_t v2 = *(const half8_t*)(hp + (size_t)s2 * DOUT);
        half8_t v3 = *(const half8_t*)(hp + (size_t)s3 * DOUT);
        half8_t v4 = *(const half8_t*)(hp + (size_t)s4 * DOUT);
        half8_t v5 = *(const half8_t*)(hp + (size_t)s5 * DOUT);
        half8_t v6 = *(const half8_t*)(hp + (size_t)s6 * DOUT);
        half8_t v7 = *(const half8_t*)(hp + (size_t)s7 * DOUT);
#pragma unroll
        for (int j = 0; j < 8; ++j) {
            acc[j] += (float)v0[j];
            acc2[j] += (float)v1[j];
            acc[j] += (float)v2[j];
            acc2[j] += (float)v3[j];
            acc[j] += (float)v4[j];
            acc2[j] += (float)v5[j];
            acc[j] += (float)v6[j];
            acc2[j] += (float)v7[j];
        }
    }
    for (; e + 2 <= end; e += 2) {
        int s0 = csr_src[e];
        int s1 = csr_src[e + 1];
        half8_t v0 = *(const half8_t*)(hp + (size_t)s0 * DOUT);
        half8_t v1 = *(const half8_t*)(hp + (size_t)s1 * DOUT);
#pragma unroll
        for (int j = 0; j < 8; ++j) {
            acc[j] += (float)v0[j];
            acc2[j] += (float)v1[j];
        }
    }
    if (e < end) {
        int s0 = csr_src[e];
        half8_t v0 = *(const half8_t*)(hp + (size_t)s0 * DOUT);
#pragma unroll
        for (int j = 0; j < 8; ++j) acc[j] += (float)v0[j];
    }
    float dn = dinv[n];
    half8_t hv = *(const half8_t*)(hp + (size_t)n * DOUT);
    float4 bv0 = *(const float4*)(b + li * 8);
    float4 bv1 = *(const float4*)(b + li * 8 + 4);
    float r[8];
    r[0] = (acc[0] + acc2[0] + (float)hv[0]) * dn + bv0.x;
    r[1] = (acc[1] + acc2[1] + (float)hv[1]) * dn + bv0.y;
    r[2] = (acc[2] + acc2[2] + (float)hv[2]) * dn + bv0.z;
    r[3] = (acc[3] + acc2[3] + (float)hv[3]) * dn + bv0.w;
    r[4] = (acc[4] + acc2[4] + (float)hv[4]) * dn + bv1.x;
    r[5] = (acc[5] + acc2[5] + (float)hv[5]) * dn + bv1.y;
    r[6] = (acc[6] + acc2[6] + (float)hv[6]) * dn + bv1.z;
    r[7] = (acc[7] + acc2[7] + (float)hv[7]) * dn + bv1.w;
    if constexpr (F16OUT) {
        half8_t oV;
#pragma unroll
        for (int j = 0; j < 8; ++j) oV[j] = (_Float16)r[j];
        *(half8_t*)((_Float16*)out + (size_t)n * DOUT + li * 8) = oV;
    } else {
        float* op = (float*)out + (size_t)n * DOUT + li * 8;
        *(float4*)op = make_float4(r[0], r[1], r[2], r[3]);
        *(float4*)(op + 4) = make_float4(r[4], r[5], r[6], r[7]);
    }
}

extern "C" void kernel_launch(void* const* d_in, const int* in_sizes, int n_in,
                              void* d_out, int out_size, void* d_ws, size_t ws_size,
                              hipStream_t stream) {
    const float* x  = (const float*)d_in[0];
    const int*   ei = (const int*)d_in[1];
    const float* W1 = (const float*)d_in[2];
    const float* b1 = (const float*)d_in[3];
    const float* W2 = (const float*)d_in[4];
    const float* b2 = (const float*)d_in[5];
    const float* W3 = (const float*)d_in[6];
    const float* b3 = (const float*)d_in[7];
    float* out = (float*)d_out;

    char* wsb = (char*)d_ws;
    size_t o = 0;
    int*            flag     = (int*)(wsb + o); o += 64 * 4;
    int*            bcur     = (int*)(wsb + o); o += 448 * 4;
    float*          dinv     = (float*)(wsb + o); o += 50048 * 4;
    int*            rowptr   = (int*)(wsb + o); o += 50048 * 4;
    unsigned short* deg16    = (unsigned short*)(wsb + o); o += 50048 * 2;
    unsigned int*   ep2      = (unsigned int*)(wsb + o); o += (size_t)NBKT * CAP * 4;
    unsigned short* csr_src  = (unsigned short*)(wsb + o); o += (size_t)NBKT * CAP * 2;
    _Float16*       Wt1      = (_Float16*)(wsb + o); o += 128 * 128 * 2;
    _Float16*       Wt2      = (_Float16*)(wsb + o); o += 128 * 128 * 2;
    _Float16*       Wt3      = (_Float16*)(wsb + o); o += 64 * 128 * 2;
    _Float16*       h        = (_Float16*)(wsb + o); o += (size_t)N_NODES * 128 * 2;
    _Float16*       agg      = (_Float16*)(wsb + o);

    const int MMB = (N_NODES + 63) / 64;   // 782

    // ---- graph preprocessing: 3 launches, no global scan ----
    init_k<<<161, 256, 0, stream>>>(ei, flag, bcur, W1, W2, W3, Wt1, Wt2, Wt3);
    phaseA_k<<<NWG_A, 256, 0, stream>>>(ei, flag, bcur, ep2);
    bucketB2_k<<<NBKT, 256, 0, stream>>>(ep2, bcur, csr_src, rowptr, deg16, dinv);

    // ---- layer 1 ----
    mm_mfma_k<128, false, float><<<MMB, 256, 0, stream>>>(x, Wt1, dinv, h);
    gather_k<128, true><<<(N_NODES + 15) / 16, 256, 0, stream>>>(h, rowptr, deg16, csr_src, dinv, b1, agg);

    // ---- layer 2 ----
    mm_mfma_k<128, true, _Float16><<<MMB, 256, 0, stream>>>(agg, Wt2, dinv, h);
    gather_k<128, true><<<(N_NODES + 15) / 16, 256, 0, stream>>>(h, rowptr, deg16, csr_src, dinv, b2, agg);

    // ---- layer 3 (to d_out, f32) ----
    mm_mfma_k<64, true, _Float16><<<MMB, 256, 0, stream>>>(agg, Wt3, dinv, h);
    gather_k<64, false><<<(N_NODES + 31) / 32, 256, 0, stream>>>(h, rowptr, deg16, csr_src, dinv, b3, out);
}